// Round 1
// baseline (1757.741 us; speedup 1.0000x reference)
//
#include <hip/hip_runtime.h>

#define J 256
#define TDIM 2048
#define NFIB 64
#define HH 4
#define DD 16
#define KOUT 192

__device__ __forceinline__ float sigf(float x) { return 1.0f / (1.0f + __expf(-x)); }

// ---------------------------------------------------------------------------
// Kernel A: fused projection. rows = N*T = 131072 of x[256].
// Outputs 200 cols per row: q(64, LN'd), k(64, LN'd + L2-norm), v(64),
// beta(4), alpha(4). Block=256, 16 rows/block, grid 8192.
// ---------------------------------------------------------------------------
__global__ __launch_bounds__(256) void proj_kernel(
    const float* __restrict__ x, const float* __restrict__ curv, const float* __restrict__ ent,
    const float* __restrict__ Wq, const float* __restrict__ Wk, const float* __restrict__ Wv,
    const float* __restrict__ Wbw, const float* __restrict__ Wbb,
    const float* __restrict__ Waw, const float* __restrict__ Wab,
    const float* __restrict__ cw, const float* __restrict__ ew,
    const float* __restrict__ lnqw, const float* __restrict__ lnqb,
    const float* __restrict__ lnkw, const float* __restrict__ lnkb,
    float* __restrict__ q_ws, float* __restrict__ k_ws, float* __restrict__ v_ws,
    float* __restrict__ beta_ws, float* __restrict__ alpha_ws)
{
    __shared__ float xs[16 * 260];   // 16 rows, stride 260 (bank 4r, conflict-free)
    __shared__ float wt[200 * 36];   // W chunk of 32 k, stride 36 (2-way = free)

    const int tid = threadIdx.x;
    const int row0 = blockIdx.x * 16;

    // stage x tile: 16 rows x 256 = 1024 float4
#pragma unroll
    for (int it = 0; it < 4; ++it) {
        int f = it * 256 + tid;
        int rr = f >> 6, s = f & 63;
        *(float4*)&xs[rr * 260 + s * 4] = *(const float4*)&x[(size_t)(row0 + rr) * J + s * 4];
    }

    const int r = tid >> 4, c = tid & 15;
    float acc[12];
#pragma unroll
    for (int cc = 0; cc < 12; ++cc) acc[cc] = 0.0f;
    float accB = 0.0f;

    for (int kc = 0; kc < 8; ++kc) {
        __syncthreads();  // also covers xs staging on first pass
        // stage W chunk: 200 rows x 32 cols = 1600 float4
        for (int f = tid; f < 1600; f += 256) {
            int wr = f >> 3, s = f & 7;
            const float* wrow;
            if (wr < 64)       wrow = Wq  + wr * J;
            else if (wr < 128) wrow = Wk  + (wr - 64) * J;
            else if (wr < 192) wrow = Wv  + (wr - 128) * J;
            else if (wr < 196) wrow = Wbw + (wr - 192) * J;
            else               wrow = Waw + (wr - 196) * J;
            *(float4*)&wt[wr * 36 + s * 4] = *(const float4*)&wrow[kc * 32 + s * 4];
        }
        __syncthreads();
#pragma unroll
        for (int mm = 0; mm < 8; ++mm) {
            float4 xv = *(const float4*)&xs[r * 260 + kc * 32 + mm * 4];
#pragma unroll
            for (int cc = 0; cc < 12; ++cc) {
                float4 wv = *(const float4*)&wt[(c + 16 * cc) * 36 + mm * 4];
                acc[cc] += xv.x * wv.x + xv.y * wv.y + xv.z * wv.z + xv.w * wv.w;
            }
            if (c < 8) {
                float4 wv = *(const float4*)&wt[(192 + c) * 36 + mm * 4];
                accB += xv.x * wv.x + xv.y * wv.y + xv.z * wv.z + xv.w * wv.w;
            }
        }
    }

    const int row_g = row0 + r;
    const int n = row_g >> 11;       // fiber
    const int t = row_g & 2047;

    // q: LN per head over d (16 lanes sharing r)
#pragma unroll
    for (int h = 0; h < 4; ++h) {
        float y = acc[h];
        float s = y;
        s += __shfl_xor(s, 1); s += __shfl_xor(s, 2); s += __shfl_xor(s, 4); s += __shfl_xor(s, 8);
        float mean = s * (1.0f / 16.0f);
        float d0 = y - mean;
        float s2 = d0 * d0;
        s2 += __shfl_xor(s2, 1); s2 += __shfl_xor(s2, 2); s2 += __shfl_xor(s2, 4); s2 += __shfl_xor(s2, 8);
        float inv = rsqrtf(s2 * (1.0f / 16.0f) + 1e-5f);
        float qn = d0 * inv * lnqw[c] + lnqb[c];
        q_ws[((n * 4 + h) * TDIM + t) * 16 + c] = qn;
    }
    // k: LN then L2 normalize
#pragma unroll
    for (int h = 0; h < 4; ++h) {
        float y = acc[4 + h];
        float s = y;
        s += __shfl_xor(s, 1); s += __shfl_xor(s, 2); s += __shfl_xor(s, 4); s += __shfl_xor(s, 8);
        float mean = s * (1.0f / 16.0f);
        float d0 = y - mean;
        float s2 = d0 * d0;
        s2 += __shfl_xor(s2, 1); s2 += __shfl_xor(s2, 2); s2 += __shfl_xor(s2, 4); s2 += __shfl_xor(s2, 8);
        float inv = rsqrtf(s2 * (1.0f / 16.0f) + 1e-5f);
        float kn = d0 * inv * lnkw[c] + lnkb[c];
        float s3 = kn * kn;
        s3 += __shfl_xor(s3, 1); s3 += __shfl_xor(s3, 2); s3 += __shfl_xor(s3, 4); s3 += __shfl_xor(s3, 8);
        kn = kn / fmaxf(sqrtf(s3), 1e-12f);
        k_ws[((n * 4 + h) * TDIM + t) * 16 + c] = kn;
    }
    // v
#pragma unroll
    for (int h = 0; h < 4; ++h)
        v_ws[((n * 4 + h) * TDIM + t) * 16 + c] = acc[8 + h];

    // beta / alpha (double sigmoid + modulation)
    if (c < 4) {
        float braw = accB + Wbb[c];
        float Kv = fminf(fabsf(curv[n >> 4]), 10.0f);
        beta_ws[(n * 4 + c) * TDIM + t] = sigf(sigf(braw) + Kv * cw[c]);
    } else if (c < 8) {
        int h = c - 4;
        float araw = accB + Wab[h];
        float Sv = fminf(fmaxf(ent[n >> 4], 0.0f), 5.0f);
        alpha_ws[(n * 4 + h) * TDIM + t] = sigf(sigf(araw) + Sv * ew[h]);
    }
}

// ---------------------------------------------------------------------------
// Kernel B: sequential delta-rule scan. One block (1 wave) per chain (n,h).
// Lane layout: row i = lane&15, col group g = lane>>4 (cols 4g..4g+3).
// M_t = M_{t-1} + (beta*v - alpha*M_{t-1}k) k^T ;  o_t = M_t q_t
// ---------------------------------------------------------------------------
__global__ __launch_bounds__(64) void scan_kernel(
    const float* __restrict__ q_ws, const float* __restrict__ k_ws, const float* __restrict__ v_ws,
    const float* __restrict__ beta_ws, const float* __restrict__ alpha_ws,
    float* __restrict__ o_ws)
{
    __shared__ float ks[64 * 16], vs[64 * 16], qs[64 * 16], os[64 * 16];
    __shared__ float bs[64], as_[64];
    const int tid = threadIdx.x;
    const int cid = blockIdx.x;
    const float* kb = k_ws + (size_t)cid * TDIM * 16;
    const float* vb = v_ws + (size_t)cid * TDIM * 16;
    const float* qb = q_ws + (size_t)cid * TDIM * 16;
    const float* bb = beta_ws + (size_t)cid * TDIM;
    const float* ab = alpha_ws + (size_t)cid * TDIM;
    float* obp = o_ws + (size_t)cid * TDIM * 16;

    const int i = tid & 15, g = tid >> 4;
    float4 M = make_float4(0.f, 0.f, 0.f, 0.f);

    for (int tc = 0; tc < 32; ++tc) {
#pragma unroll
        for (int it = 0; it < 4; ++it) {
            int f = it * 64 + tid;   // 256 float4 per tensor chunk
            ((float4*)ks)[f] = ((const float4*)(kb + tc * 1024))[f];
            ((float4*)vs)[f] = ((const float4*)(vb + tc * 1024))[f];
            ((float4*)qs)[f] = ((const float4*)(qb + tc * 1024))[f];
        }
        bs[tid] = bb[tc * 64 + tid];
        as_[tid] = ab[tc * 64 + tid];
        __syncthreads();
        for (int tt = 0; tt < 64; ++tt) {
            float4 kv = *(const float4*)&ks[tt * 16 + g * 4];
            float p = M.x * kv.x + M.y * kv.y + M.z * kv.z + M.w * kv.w;
            p += __shfl_xor(p, 16);
            p += __shfl_xor(p, 32);                 // Mk_i on all 4 g-lanes
            float w = bs[tt] * vs[tt * 16 + i] - as_[tt] * p;
            M.x += w * kv.x; M.y += w * kv.y; M.z += w * kv.z; M.w += w * kv.w;
            float4 qv = *(const float4*)&qs[tt * 16 + g * 4];
            float o = M.x * qv.x + M.y * qv.y + M.z * qv.z + M.w * qv.w;
            o += __shfl_xor(o, 16);
            o += __shfl_xor(o, 32);
            if (g == 0) os[tt * 16 + i] = o;
        }
        __syncthreads();
#pragma unroll
        for (int it = 0; it < 4; ++it) {
            int f = it * 64 + tid;
            ((float4*)(obp + tc * 1024))[f] = ((const float4*)os)[f];
        }
        // next-iter staging writes ks/vs/qs/bs/as only; os readers already
        // passed the post-loop barrier, so no extra sync needed here.
    }
}

// ---------------------------------------------------------------------------
// Kernel C: output projection. rows=(n,t), fib[row][k] = o[row][:] . out_w[k][:] + b
// Block=256, 16 rows/block, grid 8192. Writes in (B,T,P,K) layout.
// ---------------------------------------------------------------------------
__global__ __launch_bounds__(256) void outproj_kernel(
    const float* __restrict__ o_ws, const float* __restrict__ out_w,
    const float* __restrict__ out_b, float* __restrict__ out)
{
    __shared__ float ot[16 * 68];     // stride 68: bank 4r, conflict-free
    __shared__ float wtile[192 * 68]; // stride 68: 2-way (free)
    const int tid = threadIdx.x;
    const int row0 = blockIdx.x * 16;

    for (int f = tid; f < 192 * 16; f += 256) {
        int wr = f >> 4, s = f & 15;
        *(float4*)&wtile[wr * 68 + s * 4] = *(const float4*)&out_w[wr * 64 + s * 4];
    }
    {
        int rr = tid >> 4, hs = tid & 15;
        int h = hs >> 2, s = hs & 3;
        int row_g = row0 + rr;
        int n = row_g >> 11, t = row_g & 2047;
        *(float4*)&ot[rr * 68 + h * 16 + s * 4] =
            *(const float4*)&o_ws[((n * 4 + h) * TDIM + t) * 16 + s * 4];
    }
    __syncthreads();

    const int r = tid >> 4, c = tid & 15;
    float acc[12];
#pragma unroll
    for (int cc = 0; cc < 12; ++cc) acc[cc] = out_b[c + 16 * cc];
#pragma unroll
    for (int mm = 0; mm < 16; ++mm) {
        float4 ov = *(const float4*)&ot[r * 68 + mm * 4];
#pragma unroll
        for (int cc = 0; cc < 12; ++cc) {
            float4 wv = *(const float4*)&wtile[(c + 16 * cc) * 68 + mm * 4];
            acc[cc] += ov.x * wv.x + ov.y * wv.y + ov.z * wv.z + ov.w * wv.w;
        }
    }
    int row_g = row0 + r;
    int n = row_g >> 11, t = row_g & 2047;
    int b = n >> 4, p = n & 15;
    float* dst = out + ((size_t)(b * TDIM + t) * 16 + p) * KOUT;
#pragma unroll
    for (int cc = 0; cc < 12; ++cc) dst[c + 16 * cc] = acc[cc];
}

extern "C" void kernel_launch(void* const* d_in, const int* in_sizes, int n_in,
                              void* d_out, int out_size, void* d_ws, size_t ws_size,
                              hipStream_t stream) {
    (void)in_sizes; (void)n_in; (void)out_size; (void)ws_size;
    const float* x    = (const float*)d_in[0];
    const float* curv = (const float*)d_in[1];
    const float* ent  = (const float*)d_in[2];
    const float* Wq   = (const float*)d_in[3];
    const float* Wk   = (const float*)d_in[4];
    const float* Wv   = (const float*)d_in[5];
    const float* Wbw  = (const float*)d_in[6];
    const float* Wbb  = (const float*)d_in[7];
    const float* Waw  = (const float*)d_in[8];
    const float* Wab  = (const float*)d_in[9];
    const float* cw   = (const float*)d_in[10];
    const float* ew   = (const float*)d_in[11];
    const float* ow   = (const float*)d_in[12];
    const float* ob   = (const float*)d_in[13];
    const float* lnqw = (const float*)d_in[14];
    const float* lnqb = (const float*)d_in[15];
    const float* lnkw = (const float*)d_in[16];
    const float* lnkb = (const float*)d_in[17];
    float* out = (float*)d_out;

    float* ws = (float*)d_ws;
    float* q_ws     = ws;                    // 8,388,608 floats
    float* k_ws     = q_ws + 8388608;
    float* v_ws     = k_ws + 8388608;
    float* beta_ws  = v_ws + 8388608;        // 524,288
    float* alpha_ws = beta_ws + 524288;
    float* o_ws     = alpha_ws + 524288;     // 8,388,608  (total ~138.4 MB)

    proj_kernel<<<8192, 256, 0, stream>>>(x, curv, ent, Wq, Wk, Wv, Wbw, Wbb, Waw, Wab,
                                          cw, ew, lnqw, lnqb, lnkw, lnkb,
                                          q_ws, k_ws, v_ws, beta_ws, alpha_ws);
    scan_kernel<<<256, 64, 0, stream>>>(q_ws, k_ws, v_ws, beta_ws, alpha_ws, o_ws);
    outproj_kernel<<<8192, 256, 0, stream>>>(o_ws, ow, ob, out);
}

// Round 3
// 710.665 us; speedup vs baseline: 2.4734x; 2.4734x over previous
//
#include <hip/hip_runtime.h>

#define TDIM 2048

typedef __attribute__((ext_vector_type(8))) short short8;
typedef __attribute__((ext_vector_type(4))) short short4v;
typedef __attribute__((ext_vector_type(4))) float float4v;

__device__ __forceinline__ float sigf(float x) { return 1.0f / (1.0f + __expf(-x)); }

__device__ __forceinline__ unsigned short f2bf_rne(float f) {
    unsigned u = __float_as_uint(f);
    unsigned r = (u + 0x7fffu + ((u >> 16) & 1u)) >> 16;
    return (unsigned short)r;
}
__device__ __forceinline__ float bf2f(unsigned short h) {
    return __uint_as_float(((unsigned)h) << 16);
}
struct bfpair { short hi, lo; };
// split x = hi + lo, both bf16-representable
__device__ __forceinline__ bfpair cvt_split(float x) {
    bfpair p;
    unsigned short h = f2bf_rne(x);
    p.hi = (short)h;
    p.lo = (short)f2bf_rne(x - bf2f(h));
    return p;
}
// split a float4 into hi/lo short4v
__device__ __forceinline__ void split4(float4 v, short4v& hi, short4v& lo) {
    bfpair a = cvt_split(v.x), b = cvt_split(v.y), c = cvt_split(v.z), d = cvt_split(v.w);
    short4v h = {a.hi, b.hi, c.hi, d.hi};
    short4v l = {a.lo, b.lo, c.lo, d.lo};
    hi = h; lo = l;
}

#define RED16(v) { v += __shfl_xor(v, 1); v += __shfl_xor(v, 2); \
                   v += __shfl_xor(v, 4); v += __shfl_xor(v, 8); }

// LDS row layout (shorts): per row, 8 k-groups x [8 hi | 8 lo] + 8 pad = 136 shorts
// (272 B/row: 16B-aligned blocks, 4-word bank rotation per row -> 2-way = free)
#define LROW 136

// ---------------------------------------------------------------------------
// Kernel A: fused projection GEMM (split-bf16 MFMA) + LN/L2norm/sigmoid epilogue
// C[131072 x 208] = X[131072 x 256] @ Wcat^T, block = 64 rows, 4 waves,
// wave = 16 rows x 13 col-tiles. K chunks of 64.
// ---------------------------------------------------------------------------
__global__ __launch_bounds__(256, 2) void proj_kernel(
    const float* __restrict__ x, const float* __restrict__ curv, const float* __restrict__ ent,
    const float* __restrict__ Wq, const float* __restrict__ Wk, const float* __restrict__ Wv,
    const float* __restrict__ Wbw, const float* __restrict__ Wbb,
    const float* __restrict__ Waw, const float* __restrict__ Wab,
    const float* __restrict__ cw, const float* __restrict__ ew,
    const float* __restrict__ lnqw, const float* __restrict__ lnqb,
    const float* __restrict__ lnkw, const float* __restrict__ lnkb,
    float* __restrict__ q_ws, float* __restrict__ k_ws, float* __restrict__ v_ws,
    float* __restrict__ beta_ws, float* __restrict__ alpha_ws)
{
    __shared__ __align__(16) short xsh[64 * LROW];
    __shared__ __align__(16) short wsh[208 * LROW];

    const int tid = threadIdx.x;
    const int lane = tid & 63, wv = tid >> 6;
    const int row0 = blockIdx.x * 64;

    float4v acc[13];
#pragma unroll
    for (int cc = 0; cc < 13; ++cc) acc[cc] = (float4v){0.f, 0.f, 0.f, 0.f};

    for (int kc = 0; kc < 4; ++kc) {
        __syncthreads();
        // stage X chunk: 64 rows x 64 k (1024 float4, 4/thread)
#pragma unroll
        for (int it = 0; it < 4; ++it) {
            int f = it * 256 + tid;
            int rr = f >> 4, c4 = f & 15;
            float4 xv = *(const float4*)&x[(size_t)(row0 + rr) * 256 + kc * 64 + c4 * 4];
            short4v hi, lo;
            split4(xv, hi, lo);
            short* ph = &xsh[rr * LROW + (c4 >> 1) * 16 + (c4 & 1) * 4];
            *(short4v*)ph = hi;
            *(short4v*)(ph + 8) = lo;
        }
        // stage W chunk: 208 rows x 64 k (3328 float4, 13/thread); rows >=200 zero
#pragma unroll
        for (int it = 0; it < 13; ++it) {
            int f = it * 256 + tid;
            int rr = f >> 4, c4 = f & 15;
            float4 wv4 = make_float4(0.f, 0.f, 0.f, 0.f);
            const float* wrow = nullptr;
            if (rr < 64)        wrow = Wq  + (size_t)rr * 256;
            else if (rr < 128)  wrow = Wk  + (size_t)(rr - 64) * 256;
            else if (rr < 192)  wrow = Wv  + (size_t)(rr - 128) * 256;
            else if (rr < 196)  wrow = Wbw + (size_t)(rr - 192) * 256;
            else if (rr < 200)  wrow = Waw + (size_t)(rr - 196) * 256;
            if (wrow) wv4 = *(const float4*)&wrow[kc * 64 + c4 * 4];
            short4v hi, lo;
            split4(wv4, hi, lo);
            short* ph = &wsh[rr * LROW + (c4 >> 1) * 16 + (c4 & 1) * 4];
            *(short4v*)ph = hi;
            *(short4v*)(ph + 8) = lo;
        }
        __syncthreads();
        // compute: 2 MFMA-K steps of 32
#pragma unroll
        for (int ks = 0; ks < 2; ++ks) {
            const int rowA = wv * 16 + (lane & 15);
            const int g4 = ks * 4 + (lane >> 4);
            short8 ah = *(const short8*)&xsh[rowA * LROW + g4 * 16];
            short8 al = *(const short8*)&xsh[rowA * LROW + g4 * 16 + 8];
#pragma unroll
            for (int nt = 0; nt < 13; ++nt) {
                const int rowB = nt * 16 + (lane & 15);
                short8 bh = *(const short8*)&wsh[rowB * LROW + g4 * 16];
                short8 bl = *(const short8*)&wsh[rowB * LROW + g4 * 16 + 8];
                acc[nt] = __builtin_amdgcn_mfma_f32_16x16x32_bf16(ah, bh, acc[nt], 0, 0, 0);
                acc[nt] = __builtin_amdgcn_mfma_f32_16x16x32_bf16(ah, bl, acc[nt], 0, 0, 0);
                acc[nt] = __builtin_amdgcn_mfma_f32_16x16x32_bf16(al, bh, acc[nt], 0, 0, 0);
            }
        }
    }

    // Epilogue. C/D layout: col = lane&15, row = (lane>>4)*4 + reg.
    const int c = lane & 15, lq = lane >> 4;
    const float lnqw_c = lnqw[c], lnqb_c = lnqb[c];
    const float lnkw_c = lnkw[c], lnkb_c = lnkb[c];
#pragma unroll
    for (int j = 0; j < 4; ++j) {
        const int grow = row0 + wv * 16 + lq * 4 + j;
        const int n = grow >> 11, t = grow & 2047;
        // q heads: LN over the 16 cols (lanes of this 16-group)
#pragma unroll
        for (int h = 0; h < 4; ++h) {
            float y = acc[h][j];
            float s = y;  RED16(s);
            float s2 = y * y;  RED16(s2);
            float mean = s * 0.0625f;
            float var = s2 * 0.0625f - mean * mean;
            float inv = rsqrtf(var + 1e-5f);
            q_ws[((size_t)(n * 4 + h) * TDIM + t) * 16 + c] = (y - mean) * inv * lnqw_c + lnqb_c;
        }
        // k heads: LN then L2 normalize
#pragma unroll
        for (int h = 0; h < 4; ++h) {
            float y = acc[4 + h][j];
            float s = y;  RED16(s);
            float s2 = y * y;  RED16(s2);
            float mean = s * 0.0625f;
            float var = s2 * 0.0625f - mean * mean;
            float inv = rsqrtf(var + 1e-5f);
            float kn = (y - mean) * inv * lnkw_c + lnkb_c;
            float s3 = kn * kn;  RED16(s3);
            kn = kn / fmaxf(sqrtf(s3), 1e-12f);
            k_ws[((size_t)(n * 4 + h) * TDIM + t) * 16 + c] = kn;
        }
        // v heads
#pragma unroll
        for (int h = 0; h < 4; ++h)
            v_ws[((size_t)(n * 4 + h) * TDIM + t) * 16 + c] = acc[8 + h][j];
        // beta / alpha from col-tile 12 (cols 192..199)
        float yb = acc[12][j];
        if (c < 4) {
            float Kv = fminf(fabsf(curv[n >> 4]), 10.0f);
            beta_ws[(size_t)(n * 4 + c) * TDIM + t] = sigf(sigf(yb + Wbb[c]) + Kv * cw[c]);
        } else if (c < 8) {
            int h = c - 4;
            float Sv = fminf(fmaxf(ent[n >> 4], 0.0f), 5.0f);
            alpha_ws[(size_t)(n * 4 + h) * TDIM + t] = sigf(sigf(yb + Wab[h]) + Sv * ew[h]);
        }
    }
}

// ---------------------------------------------------------------------------
// Kernel B: sequential delta-rule scan, 1 wave per chain (n,h).
// Lane: row i = lane&15, col-group g = lane>>4 (cols 4g..4g+3 of M).
// Software-pipelined: t+1 LDS reads prefetched; next chunk prefetched into
// registers over the compute loop. o_t = M_{t-1} q_t + w * (k.q) keeps the
// output dot off the recurrence critical path.
// ---------------------------------------------------------------------------
__global__ __launch_bounds__(64) void scan_kernel(
    const float* __restrict__ q_ws, const float* __restrict__ k_ws, const float* __restrict__ v_ws,
    const float* __restrict__ beta_ws, const float* __restrict__ alpha_ws,
    float* __restrict__ o_ws)
{
    __shared__ float ks[64 * 16], vs[64 * 16], qs[64 * 16], os[64 * 16];
    __shared__ float bs[64], as_[64];
    const int tid = threadIdx.x;
    const int cid = blockIdx.x;
    const float* kb = k_ws + (size_t)cid * TDIM * 16;
    const float* vb = v_ws + (size_t)cid * TDIM * 16;
    const float* qb = q_ws + (size_t)cid * TDIM * 16;
    const float* bb = beta_ws + (size_t)cid * TDIM;
    const float* ab = alpha_ws + (size_t)cid * TDIM;
    float* obp = o_ws + (size_t)cid * TDIM * 16;

    const int i = tid & 15, g = tid >> 4;
    float4 M = make_float4(0.f, 0.f, 0.f, 0.f);

    float4 rk[4], rv[4], rq[4];
    float rb, ra;
    // stage chunk 0
#pragma unroll
    for (int it = 0; it < 4; ++it) {
        int f = it * 64 + tid;
        rk[it] = ((const float4*)kb)[f];
        rv[it] = ((const float4*)vb)[f];
        rq[it] = ((const float4*)qb)[f];
    }
    rb = bb[tid]; ra = ab[tid];
#pragma unroll
    for (int it = 0; it < 4; ++it) {
        int f = it * 64 + tid;
        ((float4*)ks)[f] = rk[it];
        ((float4*)vs)[f] = rv[it];
        ((float4*)qs)[f] = rq[it];
    }
    bs[tid] = rb; as_[tid] = ra;
    __syncthreads();

    for (int tc = 0; tc < 32; ++tc) {
        // prefetch chunk tc+1 into registers (wrap on last iter; values unused)
        const int tcn = (tc + 1) & 31;
#pragma unroll
        for (int it = 0; it < 4; ++it) {
            int f = it * 64 + tid;
            rk[it] = ((const float4*)(kb + tcn * 1024))[f];
            rv[it] = ((const float4*)(vb + tcn * 1024))[f];
            rq[it] = ((const float4*)(qb + tcn * 1024))[f];
        }
        rb = bb[tcn * 64 + tid]; ra = ab[tcn * 64 + tid];

        float4 kv = *(const float4*)&ks[g * 4];
        float4 qv = *(const float4*)&qs[g * 4];
        float vv = vs[i];
        float bt = bs[0], at = as_[0];
#pragma unroll 4
        for (int tt = 0; tt < 64; ++tt) {
            const int tn = (tt + 1) & 63;
            float4 kvn = *(const float4*)&ks[tn * 16 + g * 4];
            float4 qvn = *(const float4*)&qs[tn * 16 + g * 4];
            float vvn = vs[tn * 16 + i];
            float btn = bs[tn], atn = as_[tn];

            float p  = M.x * kv.x + M.y * kv.y + M.z * kv.z + M.w * kv.w;
            float r  = M.x * qv.x + M.y * qv.y + M.z * qv.z + M.w * qv.w;
            float kq = kv.x * qv.x + kv.y * qv.y + kv.z * qv.z + kv.w * qv.w;
            p  += __shfl_xor(p, 16);  p  += __shfl_xor(p, 32);
            r  += __shfl_xor(r, 16);  r  += __shfl_xor(r, 32);
            kq += __shfl_xor(kq, 16); kq += __shfl_xor(kq, 32);
            float w = bt * vv - at * p;
            M.x += w * kv.x; M.y += w * kv.y; M.z += w * kv.z; M.w += w * kv.w;
            if (g == 0) os[tt * 16 + i] = r + w * kq;

            kv = kvn; qv = qvn; vv = vvn; bt = btn; at = atn;
        }
        __syncthreads();
        // flush o chunk, then overwrite LDS with prefetched chunk
#pragma unroll
        for (int it = 0; it < 4; ++it) {
            int f = it * 64 + tid;
            ((float4*)(obp + tc * 1024))[f] = ((const float4*)os)[f];
            ((float4*)ks)[f] = rk[it];
            ((float4*)vs)[f] = rv[it];
            ((float4*)qs)[f] = rq[it];
        }
        bs[tid] = rb; as_[tid] = ra;
        __syncthreads();
    }
}

// ---------------------------------------------------------------------------
// Kernel C: output projection (split-bf16 MFMA).
// C[131072 x 192] = O[131072 x 64] @ out_w^T + b. Block = 64 rows, K = 64.
// ---------------------------------------------------------------------------
__global__ __launch_bounds__(256, 2) void outproj_kernel(
    const float* __restrict__ o_ws, const float* __restrict__ ow,
    const float* __restrict__ ob, float* __restrict__ out)
{
    __shared__ __align__(16) short osh[64 * LROW];
    __shared__ __align__(16) short wsh[192 * LROW];
    const int tid = threadIdx.x;
    const int lane = tid & 63, wv = tid >> 6;
    const int row0 = blockIdx.x * 64;

    float4v acc[12];
#pragma unroll
    for (int cc = 0; cc < 12; ++cc) acc[cc] = (float4v){0.f, 0.f, 0.f, 0.f};

    // stage O: 64 rows x 64 cols (col = h*16+d gathered from 4 chain rows)
#pragma unroll
    for (int it = 0; it < 4; ++it) {
        int f = it * 256 + tid;
        int rr = f >> 4, c4 = f & 15;
        int grow = row0 + rr;
        int n = grow >> 11, t = grow & 2047;
        int h = c4 >> 2, d4 = c4 & 3;
        float4 xv = *(const float4*)&o_ws[((size_t)(n * 4 + h) * TDIM + t) * 16 + d4 * 4];
        short4v hi, lo;
        split4(xv, hi, lo);
        short* ph = &osh[rr * LROW + (c4 >> 1) * 16 + (c4 & 1) * 4];
        *(short4v*)ph = hi;
        *(short4v*)(ph + 8) = lo;
    }
    // stage W: 192 x 64 (3072 float4, 12/thread)
#pragma unroll
    for (int it = 0; it < 12; ++it) {
        int f = it * 256 + tid;
        int rr = f >> 4, c4 = f & 15;
        float4 wv4 = *(const float4*)&ow[(size_t)rr * 64 + c4 * 4];
        short4v hi, lo;
        split4(wv4, hi, lo);
        short* ph = &wsh[rr * LROW + (c4 >> 1) * 16 + (c4 & 1) * 4];
        *(short4v*)ph = hi;
        *(short4v*)(ph + 8) = lo;
    }
    __syncthreads();

#pragma unroll
    for (int ks = 0; ks < 2; ++ks) {
        const int rowA = wv * 16 + (lane & 15);
        const int g4 = ks * 4 + (lane >> 4);
        short8 ah = *(const short8*)&osh[rowA * LROW + g4 * 16];
        short8 al = *(const short8*)&osh[rowA * LROW + g4 * 16 + 8];
#pragma unroll
        for (int nt = 0; nt < 12; ++nt) {
            const int rowB = nt * 16 + (lane & 15);
            short8 bh = *(const short8*)&wsh[rowB * LROW + g4 * 16];
            short8 bl = *(const short8*)&wsh[rowB * LROW + g4 * 16 + 8];
            acc[nt] = __builtin_amdgcn_mfma_f32_16x16x32_bf16(ah, bh, acc[nt], 0, 0, 0);
            acc[nt] = __builtin_amdgcn_mfma_f32_16x16x32_bf16(ah, bl, acc[nt], 0, 0, 0);
            acc[nt] = __builtin_amdgcn_mfma_f32_16x16x32_bf16(al, bh, acc[nt], 0, 0, 0);
        }
    }

    const int c = lane & 15, lq = lane >> 4;
#pragma unroll
    for (int nt = 0; nt < 12; ++nt) {
        float bias = ob[nt * 16 + c];
#pragma unroll
        for (int j = 0; j < 4; ++j) {
            int grow = row0 + wv * 16 + lq * 4 + j;
            int n = grow >> 11, t = grow & 2047;
            int b = n >> 4, p = n & 15;
            out[((size_t)(b * TDIM + t) * 16 + p) * 192 + nt * 16 + c] = acc[nt][j] + bias;
        }
    }
}

extern "C" void kernel_launch(void* const* d_in, const int* in_sizes, int n_in,
                              void* d_out, int out_size, void* d_ws, size_t ws_size,
                              hipStream_t stream) {
    (void)in_sizes; (void)n_in; (void)out_size; (void)ws_size;
    const float* x    = (const float*)d_in[0];
    const float* curv = (const float*)d_in[1];
    const float* ent  = (const float*)d_in[2];
    const float* Wq   = (const float*)d_in[3];
    const float* Wk   = (const float*)d_in[4];
    const float* Wv   = (const float*)d_in[5];
    const float* Wbw  = (const float*)d_in[6];
    const float* Wbb  = (const float*)d_in[7];
    const float* Waw  = (const float*)d_in[8];
    const float* Wab  = (const float*)d_in[9];
    const float* cw   = (const float*)d_in[10];
    const float* ew   = (const float*)d_in[11];
    const float* ow   = (const float*)d_in[12];
    const float* ob   = (const float*)d_in[13];
    const float* lnqw = (const float*)d_in[14];
    const float* lnqb = (const float*)d_in[15];
    const float* lnkw = (const float*)d_in[16];
    const float* lnkb = (const float*)d_in[17];
    float* out = (float*)d_out;

    float* ws = (float*)d_ws;
    float* q_ws     = ws;                    // 8,388,608 floats
    float* k_ws     = q_ws + 8388608;
    float* v_ws     = k_ws + 8388608;
    float* beta_ws  = v_ws + 8388608;        // 524,288
    float* alpha_ws = beta_ws + 524288;
    float* o_ws     = alpha_ws + 524288;     // 8,388,608

    proj_kernel<<<2048, 256, 0, stream>>>(x, curv, ent, Wq, Wk, Wv, Wbw, Wbb, Waw, Wab,
                                          cw, ew, lnqw, lnqb, lnkw, lnkb,
                                          q_ws, k_ws, v_ws, beta_ws, alpha_ws);
    scan_kernel<<<256, 64, 0, stream>>>(q_ws, k_ws, v_ws, beta_ws, alpha_ws, o_ws);
    outproj_kernel<<<2048, 256, 0, stream>>>(o_ws, ow, ob, out);
}

// Round 4
// 619.640 us; speedup vs baseline: 2.8367x; 1.1469x over previous
//
#include <hip/hip_runtime.h>

#define TDIM 2048

typedef __attribute__((ext_vector_type(8))) short short8;
typedef __attribute__((ext_vector_type(4))) short short4v;
typedef __attribute__((ext_vector_type(4))) float float4v;

__device__ __forceinline__ float sigf(float x) { return 1.0f / (1.0f + __expf(-x)); }

__device__ __forceinline__ unsigned short f2bf_rne(float f) {
    unsigned u = __float_as_uint(f);
    unsigned r = (u + 0x7fffu + ((u >> 16) & 1u)) >> 16;
    return (unsigned short)r;
}
__device__ __forceinline__ float bf2f(unsigned short h) {
    return __uint_as_float(((unsigned)h) << 16);
}
struct bfpair { short hi, lo; };
__device__ __forceinline__ bfpair cvt_split(float x) {
    bfpair p;
    unsigned short h = f2bf_rne(x);
    p.hi = (short)h;
    p.lo = (short)f2bf_rne(x - bf2f(h));
    return p;
}
__device__ __forceinline__ void split4(float4 v, short4v& hi, short4v& lo) {
    bfpair a = cvt_split(v.x), b = cvt_split(v.y), c = cvt_split(v.z), d = cvt_split(v.w);
    short4v h = {a.hi, b.hi, c.hi, d.hi};
    short4v l = {a.lo, b.lo, c.lo, d.lo};
    hi = h; lo = l;
}

#define RED16(v) { v += __shfl_xor(v, 1); v += __shfl_xor(v, 2); \
                   v += __shfl_xor(v, 4); v += __shfl_xor(v, 8); }

__device__ __forceinline__ float dot4f(float4 a, float4 b) {
    return fmaf(a.w, b.w, fmaf(a.z, b.z, fmaf(a.y, b.y, a.x * b.x)));
}
__device__ __forceinline__ float red4g(float v) {
    v += __shfl_xor(v, 16);
    v += __shfl_xor(v, 32);
    return v;
}

// LDS row layout (shorts): 8 k-groups x [8 hi | 8 lo] + 8 pad = 136 shorts
#define LROW 136

// ---------------------------------------------------------------------------
// prep_w: pre-split concatenated W (200x256, rows>=200 zero-padded to 208)
// into the proj LDS image: [kc 0..3][row 0..207][gg 0..7][hi8|lo8].
// 6656 units of 16 shorts.
// ---------------------------------------------------------------------------
__global__ __launch_bounds__(256) void prep_w_kernel(
    const float* __restrict__ Wq, const float* __restrict__ Wk, const float* __restrict__ Wv,
    const float* __restrict__ Wbw, const float* __restrict__ Waw,
    short* __restrict__ wimg)
{
    int u = blockIdx.x * 256 + threadIdx.x;
    if (u >= 6656) return;
    int kc = u / 1664, rem = u % 1664;
    int rr = rem >> 3, gg = rem & 7;
    const float* wrow = nullptr;
    if (rr < 64)       wrow = Wq  + (size_t)rr * 256;
    else if (rr < 128) wrow = Wk  + (size_t)(rr - 64) * 256;
    else if (rr < 192) wrow = Wv  + (size_t)(rr - 128) * 256;
    else if (rr < 196) wrow = Wbw + (size_t)(rr - 192) * 256;
    else if (rr < 200) wrow = Waw + (size_t)(rr - 196) * 256;
    short* dst = wimg + (size_t)u * 16;
#pragma unroll
    for (int s = 0; s < 8; ++s) {
        float v = wrow ? wrow[kc * 64 + gg * 8 + s] : 0.0f;
        bfpair p = cvt_split(v);
        dst[s] = p.hi; dst[8 + s] = p.lo;
    }
}

// prep_ow: same for out_w (192x64): [row 0..191][gg 0..7][hi8|lo8], 1536 units.
__global__ __launch_bounds__(256) void prep_ow_kernel(
    const float* __restrict__ ow, short* __restrict__ owimg)
{
    int u = blockIdx.x * 256 + threadIdx.x;
    if (u >= 1536) return;
    int rr = u >> 3, gg = u & 7;
    short* dst = owimg + (size_t)u * 16;
#pragma unroll
    for (int s = 0; s < 8; ++s) {
        bfpair p = cvt_split(ow[(size_t)rr * 64 + gg * 8 + s]);
        dst[s] = p.hi; dst[8 + s] = p.lo;
    }
}

// ---------------------------------------------------------------------------
// Kernel A: fused projection GEMM (split-bf16 MFMA) + LN/L2norm/sigmoid epilogue
// ---------------------------------------------------------------------------
__global__ __launch_bounds__(256, 2) void proj_kernel(
    const float* __restrict__ x, const float* __restrict__ curv, const float* __restrict__ ent,
    const short* __restrict__ wimg,
    const float* __restrict__ Wbb, const float* __restrict__ Wab,
    const float* __restrict__ cw, const float* __restrict__ ew,
    const float* __restrict__ lnqw, const float* __restrict__ lnqb,
    const float* __restrict__ lnkw, const float* __restrict__ lnkb,
    float* __restrict__ q_ws, float* __restrict__ k_ws, float* __restrict__ v_ws,
    float* __restrict__ beta_ws, float* __restrict__ alpha_ws)
{
    __shared__ __align__(16) short xsh[64 * LROW];
    __shared__ __align__(16) short wsh[208 * LROW];

    const int tid = threadIdx.x;
    const int lane = tid & 63, wv = tid >> 6;
    const int row0 = blockIdx.x * 64;

    float4v acc[13];
#pragma unroll
    for (int cc = 0; cc < 13; ++cc) acc[cc] = (float4v){0.f, 0.f, 0.f, 0.f};

    for (int kc = 0; kc < 4; ++kc) {
        __syncthreads();
        // stage X chunk: 64 rows x 64 k (split in-kernel; each row converted once)
#pragma unroll
        for (int it = 0; it < 4; ++it) {
            int f = it * 256 + tid;
            int rr = f >> 4, c4 = f & 15;
            float4 xv = *(const float4*)&x[(size_t)(row0 + rr) * 256 + kc * 64 + c4 * 4];
            short4v hi, lo;
            split4(xv, hi, lo);
            short* ph = &xsh[rr * LROW + (c4 >> 1) * 16 + (c4 & 1) * 4];
            *(short4v*)ph = hi;
            *(short4v*)(ph + 8) = lo;
        }
        // stage W chunk: pure copy from pre-split image (3328 x 16B)
        {
            const int4* wsrc = (const int4*)(wimg + (size_t)kc * 26624);
#pragma unroll
            for (int it = 0; it < 13; ++it) {
                int f = it * 256 + tid;
                int4 tv = wsrc[f];
                int row = f >> 4, idx = f & 15;
                *(int4*)&wsh[row * LROW + (idx >> 1) * 16 + (idx & 1) * 8] = tv;
            }
        }
        __syncthreads();
#pragma unroll
        for (int ks = 0; ks < 2; ++ks) {
            const int rowA = wv * 16 + (lane & 15);
            const int g4 = ks * 4 + (lane >> 4);
            short8 ah = *(const short8*)&xsh[rowA * LROW + g4 * 16];
            short8 al = *(const short8*)&xsh[rowA * LROW + g4 * 16 + 8];
#pragma unroll
            for (int nt = 0; nt < 13; ++nt) {
                const int rowB = nt * 16 + (lane & 15);
                short8 bh = *(const short8*)&wsh[rowB * LROW + g4 * 16];
                short8 bl = *(const short8*)&wsh[rowB * LROW + g4 * 16 + 8];
                acc[nt] = __builtin_amdgcn_mfma_f32_16x16x32_bf16(ah, bh, acc[nt], 0, 0, 0);
                acc[nt] = __builtin_amdgcn_mfma_f32_16x16x32_bf16(ah, bl, acc[nt], 0, 0, 0);
                acc[nt] = __builtin_amdgcn_mfma_f32_16x16x32_bf16(al, bh, acc[nt], 0, 0, 0);
            }
        }
    }

    // Epilogue. C/D layout: col = lane&15, row = (lane>>4)*4 + reg.
    const int c = lane & 15, lq = lane >> 4;
    const float lnqw_c = lnqw[c], lnqb_c = lnqb[c];
    const float lnkw_c = lnkw[c], lnkb_c = lnkb[c];
#pragma unroll
    for (int j = 0; j < 4; ++j) {
        const int grow = row0 + wv * 16 + lq * 4 + j;
        const int n = grow >> 11, t = grow & 2047;
#pragma unroll
        for (int h = 0; h < 4; ++h) {
            float y = acc[h][j];
            float s = y;  RED16(s);
            float s2 = y * y;  RED16(s2);
            float mean = s * 0.0625f;
            float var = s2 * 0.0625f - mean * mean;
            float inv = rsqrtf(var + 1e-5f);
            q_ws[((size_t)(n * 4 + h) * TDIM + t) * 16 + c] = (y - mean) * inv * lnqw_c + lnqb_c;
        }
#pragma unroll
        for (int h = 0; h < 4; ++h) {
            float y = acc[4 + h][j];
            float s = y;  RED16(s);
            float s2 = y * y;  RED16(s2);
            float mean = s * 0.0625f;
            float var = s2 * 0.0625f - mean * mean;
            float inv = rsqrtf(var + 1e-5f);
            float kn = (y - mean) * inv * lnkw_c + lnkb_c;
            float s3 = kn * kn;  RED16(s3);
            kn = kn / fmaxf(sqrtf(s3), 1e-12f);
            k_ws[((size_t)(n * 4 + h) * TDIM + t) * 16 + c] = kn;
        }
#pragma unroll
        for (int h = 0; h < 4; ++h)
            v_ws[((size_t)(n * 4 + h) * TDIM + t) * 16 + c] = acc[8 + h][j];
        float yb = acc[12][j];
        if (c < 4) {
            float Kv = fminf(fabsf(curv[n >> 4]), 10.0f);
            beta_ws[(size_t)(n * 4 + c) * TDIM + t] = sigf(sigf(yb + Wbb[c]) + Kv * cw[c]);
        } else if (c < 8) {
            int h = c - 4;
            float Sv = fminf(fmaxf(ent[n >> 4], 0.0f), 5.0f);
            alpha_ws[(size_t)(n * 4 + h) * TDIM + t] = sigf(sigf(yb + Wab[h]) + Sv * ew[h]);
        }
    }
}

// ---------------------------------------------------------------------------
// Kernel B: delta-rule scan, 1 wave/chain. Lane: row i=lane&15, col-quad
// g=lane>>4 (M[i][4g..4g+3]). 2-step-stale reassociation:
//   p_t = u'_t + w_{t-2} C2_t + w_{t-1} C_t,  u'_t = M_{t-3} k_t
//   o_t = r'_t + w_{t-2} E2_t + w_{t-1} e_t + w_t d_t,  r'_t = M_{t-3} q_t
// with C_t=k_{t-1}.k_t, C2_t=k_{t-2}.k_t, d_t=k_t.q_t, e_t=k_{t-1}.q_t,
// E2_t=k_{t-2}.q_t precomputed per-chunk (lane=timestep table pass).
// Critical recurrence: w -> p -> w = 2 fma; shfl reductions have 2-step slack.
// ---------------------------------------------------------------------------
__global__ __launch_bounds__(64) void scan_kernel(
    const float* __restrict__ q_ws, const float* __restrict__ k_ws, const float* __restrict__ v_ws,
    const float* __restrict__ beta_ws, const float* __restrict__ alpha_ws,
    float* __restrict__ o_ws)
{
    __shared__ float ks[128 * 16], qs[128 * 16], bvs[128 * 16];
    __shared__ float tbl[128 * 8];
    __shared__ float os[64 * 16];
    const int tid = threadIdx.x;
    const int cid = blockIdx.x;
    const int i = tid & 15, g = tid >> 4;
    const float* kb = k_ws + (size_t)cid * TDIM * 16;
    const float* qb = q_ws + (size_t)cid * TDIM * 16;
    const float* vb = v_ws + (size_t)cid * TDIM * 16;
    const float* bb = beta_ws + (size_t)cid * TDIM;
    const float* ab = alpha_ws + (size_t)cid * TDIM;
    float* obp = o_ws + (size_t)cid * TDIM * 16;

    // zero LDS so circular reads before t=0 are clean zeros (not NaN garbage)
    for (int f = tid; f < 128 * 16; f += 64) { ks[f] = 0.f; qs[f] = 0.f; bvs[f] = 0.f; }
    for (int f = tid; f < 128 * 8; f += 64) tbl[f] = 0.f;
    __syncthreads();

    float4 kr[4], qr[4], vr[4]; float be = 0.f, alp = 0.f;
    auto load_stage = [&](int s) {
        size_t t0 = (size_t)s * 64 + tid;   // overruns at s=32 stay in ws (finite)
        const float4* kp = (const float4*)(kb + t0 * 16);
        const float4* qp = (const float4*)(qb + t0 * 16);
        const float4* vp = (const float4*)(vb + t0 * 16);
#pragma unroll
        for (int j = 0; j < 4; ++j) { kr[j] = kp[j]; qr[j] = qp[j]; vr[j] = vp[j]; }
        be = bb[t0]; alp = ab[t0];
    };
    auto commit_stage = [&](int s) {
        int r = (s & 1) * 64 + tid;
#pragma unroll
        for (int j = 0; j < 4; ++j) {
            *(float4*)&ks[r * 16 + 4 * j] = kr[j];
            *(float4*)&qs[r * 16 + 4 * j] = qr[j];
            float4 bv4 = make_float4(be * vr[j].x, be * vr[j].y, be * vr[j].z, be * vr[j].w);
            *(float4*)&bvs[r * 16 + 4 * j] = bv4;
        }
        tbl[r * 8 + 5] = alp;
    };
    auto table_pass = [&](int s) {
        int r0 = (s & 1) * 64 + tid;
        int rm1 = (r0 - 1) & 127, rm2 = (r0 - 2) & 127;
        float C = 0.f, C2 = 0.f, d = 0.f, e = 0.f, E2 = 0.f;
#pragma unroll
        for (int j = 0; j < 4; ++j) {
            float4 kt  = *(float4*)&ks[r0 * 16 + 4 * j];
            float4 km1 = *(float4*)&ks[rm1 * 16 + 4 * j];
            float4 km2 = *(float4*)&ks[rm2 * 16 + 4 * j];
            float4 qt  = *(float4*)&qs[r0 * 16 + 4 * j];
            C  += dot4f(km1, kt);
            C2 += dot4f(km2, kt);
            d  += dot4f(kt,  qt);
            e  += dot4f(km1, qt);
            E2 += dot4f(km2, qt);
        }
        *(float4*)&tbl[r0 * 8] = make_float4(C, C2, d, e);
        tbl[r0 * 8 + 4] = E2;
    };

    // chunk 0
    load_stage(0);
    commit_stage(0);
    __syncthreads();
    table_pass(0);
    __syncthreads();

    // persistent recurrence state
    float4 M4 = make_float4(0.f, 0.f, 0.f, 0.f);    // M[i][4g..4g+3], lags 2 steps
    float w1 = 0.f, w2 = 0.f;                        // w_{t-1}, w_{t-2}
    float4 k4m1 = make_float4(0.f, 0.f, 0.f, 0.f);   // k_{t-1} quad (for M update)
    float4 k4_0 = *(float4*)&ks[0 * 16 + 4 * g];
    float4 k4p1 = *(float4*)&ks[1 * 16 + 4 * g];
    float4 q4p1 = *(float4*)&qs[1 * 16 + 4 * g];
    float up_cur = 0.f, rp_cur = 0.f;                // u'_t, r'_t
    float4 ta0 = *(float4*)&tbl[0];
    float C_c = ta0.x, C2_c = ta0.y, d_c = ta0.z, e_c = ta0.w;
    float E2_c = tbl[4], al_c = tbl[5];
    float bv_c = bvs[i];

    int t = 0;
    auto step = [&]() {
        int rp2 = (t + 2) & 127, rp1 = (t + 1) & 127;
        float4 k4in = *(float4*)&ks[rp2 * 16 + 4 * g];
        float4 q4in = *(float4*)&qs[rp2 * 16 + 4 * g];
        float4 tain = *(float4*)&tbl[rp1 * 8];
        float E2in = tbl[rp1 * 8 + 4], alin = tbl[rp1 * 8 + 5];
        float bvin = bvs[rp1 * 16 + i];
        // u'_{t+1}, r'_{t+1} from M_{t-2} (pre-update) — 2 steps of slack
        float up = red4g(dot4f(M4, k4p1));
        float rp = red4g(dot4f(M4, q4p1));
        // lazy M update: M_{t-2} -> M_{t-1}
        M4.x = fmaf(w1, k4m1.x, M4.x);
        M4.y = fmaf(w1, k4m1.y, M4.y);
        M4.z = fmaf(w1, k4m1.z, M4.z);
        M4.w = fmaf(w1, k4m1.w, M4.w);
        // critical chain: 2 fma
        float p = fmaf(w1, C_c, fmaf(w2, C2_c, up_cur));
        float w0 = fmaf(-al_c, p, bv_c);
        float o = fmaf(w0, d_c, fmaf(w1, e_c, fmaf(w2, E2_c, rp_cur)));
        if (g == 0) os[(t & 63) * 16 + i] = o;
        // rotate
        w2 = w1; w1 = w0;
        k4m1 = k4_0; k4_0 = k4p1; k4p1 = k4in;
        q4p1 = q4in;
        up_cur = up; rp_cur = rp;
        C_c = tain.x; C2_c = tain.y; d_c = tain.z; e_c = tain.w;
        E2_c = E2in; al_c = alin; bv_c = bvin;
        ++t;
    };

    for (int s = 0; s < 32; ++s) {
        load_stage(s + 1);                 // global loads land over next ~32 steps
#pragma unroll 4
        for (int u = 0; u < 32; ++u) step();
        commit_stage(s + 1);               // mid-chunk: vmcnt long satisfied
#pragma unroll 4
        for (int u = 0; u < 16; ++u) step();
        table_pass(s + 1);                 // needs commit done; rows t-1,t-2 intact
#pragma unroll 4
        for (int u = 0; u < 16; ++u) step();
        // flush o chunk (DS in-order: all 64 os rows written)
#pragma unroll
        for (int j = 0; j < 4; ++j) {
            float4 ov = *(float4*)&os[(tid * 4 + j) * 4];
            *(float4*)&obp[(size_t)s * 1024 + (tid * 4 + j) * 4] = ov;
        }
    }
}

// ---------------------------------------------------------------------------
// Kernel C: output projection (split-bf16 MFMA), W from pre-split image.
// ---------------------------------------------------------------------------
__global__ __launch_bounds__(256, 2) void outproj_kernel(
    const float* __restrict__ o_ws, const short* __restrict__ owimg,
    const float* __restrict__ ob, float* __restrict__ out)
{
    __shared__ __align__(16) short osh[64 * LROW];
    __shared__ __align__(16) short wsh[192 * LROW];
    const int tid = threadIdx.x;
    const int lane = tid & 63, wv = tid >> 6;
    const int row0 = blockIdx.x * 64;

    float4v acc[12];
#pragma unroll
    for (int cc = 0; cc < 12; ++cc) acc[cc] = (float4v){0.f, 0.f, 0.f, 0.f};

#pragma unroll
    for (int it = 0; it < 4; ++it) {
        int f = it * 256 + tid;
        int rr = f >> 4, c4 = f & 15;
        int grow = row0 + rr;
        int n = grow >> 11, t = grow & 2047;
        int h = c4 >> 2, d4 = c4 & 3;
        float4 xv = *(const float4*)&o_ws[((size_t)(n * 4 + h) * TDIM + t) * 16 + d4 * 4];
        short4v hi, lo;
        split4(xv, hi, lo);
        short* ph = &osh[rr * LROW + (c4 >> 1) * 16 + (c4 & 1) * 4];
        *(short4v*)ph = hi;
        *(short4v*)(ph + 8) = lo;
    }
    {
        const int4* wsrc = (const int4*)owimg;
#pragma unroll
        for (int it = 0; it < 12; ++it) {
            int f = it * 256 + tid;
            int4 tv = wsrc[f];
            int row = f >> 4, idx = f & 15;
            *(int4*)&wsh[row * LROW + (idx >> 1) * 16 + (idx & 1) * 8] = tv;
        }
    }
    __syncthreads();

#pragma unroll
    for (int ks = 0; ks < 2; ++ks) {
        const int rowA = wv * 16 + (lane & 15);
        const int g4 = ks * 4 + (lane >> 4);
        short8 ah = *(const short8*)&osh[rowA * LROW + g4 * 16];
        short8 al = *(const short8*)&osh[rowA * LROW + g4 * 16 + 8];
#pragma unroll
        for (int nt = 0; nt < 12; ++nt) {
            const int rowB = nt * 16 + (lane & 15);
            short8 bh = *(const short8*)&wsh[rowB * LROW + g4 * 16];
            short8 bl = *(const short8*)&wsh[rowB * LROW + g4 * 16 + 8];
            acc[nt] = __builtin_amdgcn_mfma_f32_16x16x32_bf16(ah, bh, acc[nt], 0, 0, 0);
            acc[nt] = __builtin_amdgcn_mfma_f32_16x16x32_bf16(ah, bl, acc[nt], 0, 0, 0);
            acc[nt] = __builtin_amdgcn_mfma_f32_16x16x32_bf16(al, bh, acc[nt], 0, 0, 0);
        }
    }

    const int c = lane & 15, lq = lane >> 4;
#pragma unroll
    for (int nt = 0; nt < 12; ++nt) {
        float bias = ob[nt * 16 + c];
#pragma unroll
        for (int j = 0; j < 4; ++j) {
            int grow = row0 + wv * 16 + lq * 4 + j;
            int n = grow >> 11, t = grow & 2047;
            int b = n >> 4, p = n & 15;
            out[((size_t)(b * TDIM + t) * 16 + p) * 192 + nt * 16 + c] = acc[nt][j] + bias;
        }
    }
}

extern "C" void kernel_launch(void* const* d_in, const int* in_sizes, int n_in,
                              void* d_out, int out_size, void* d_ws, size_t ws_size,
                              hipStream_t stream) {
    (void)in_sizes; (void)n_in; (void)out_size; (void)ws_size;
    const float* x    = (const float*)d_in[0];
    const float* curv = (const float*)d_in[1];
    const float* ent  = (const float*)d_in[2];
    const float* Wq   = (const float*)d_in[3];
    const float* Wk   = (const float*)d_in[4];
    const float* Wv   = (const float*)d_in[5];
    const float* Wbw  = (const float*)d_in[6];
    const float* Wbb  = (const float*)d_in[7];
    const float* Waw  = (const float*)d_in[8];
    const float* Wab  = (const float*)d_in[9];
    const float* cw   = (const float*)d_in[10];
    const float* ew   = (const float*)d_in[11];
    const float* ow   = (const float*)d_in[12];
    const float* ob   = (const float*)d_in[13];
    const float* lnqw = (const float*)d_in[14];
    const float* lnqb = (const float*)d_in[15];
    const float* lnkw = (const float*)d_in[16];
    const float* lnkb = (const float*)d_in[17];
    float* out = (float*)d_out;

    float* ws = (float*)d_ws;
    float* q_ws     = ws;                    // 8,388,608 floats
    float* k_ws     = q_ws + 8388608;
    float* v_ws     = k_ws + 8388608;
    float* beta_ws  = v_ws + 8388608;        // 524,288
    float* alpha_ws = beta_ws + 524288;
    float* o_ws     = alpha_ws + 524288;     // 8,388,608

    // Overlays (no extra ws): wimg lives at o_ws head (dead before scan writes
    // o_ws); owimg lives at q_ws head (written after scan, q_ws then dead).
    short* wimg  = (short*)o_ws;             // 106,496 shorts
    short* owimg = (short*)q_ws;             // 24,576 shorts

    prep_w_kernel<<<26, 256, 0, stream>>>(Wq, Wk, Wv, Wbw, Waw, wimg);
    proj_kernel<<<2048, 256, 0, stream>>>(x, curv, ent, wimg, Wbb, Wab,
                                          cw, ew, lnqw, lnqb, lnkw, lnkb,
                                          q_ws, k_ws, v_ws, beta_ws, alpha_ws);
    scan_kernel<<<256, 64, 0, stream>>>(q_ws, k_ws, v_ws, beta_ws, alpha_ws, o_ws);
    prep_ow_kernel<<<6, 256, 0, stream>>>(ow, owimg);
    outproj_kernel<<<2048, 256, 0, stream>>>(o_ws, owimg, ob, out);
}